// Round 4
// baseline (108.288 us; speedup 1.0000x reference)
//
#include <hip/hip_runtime.h>
#include <hip/hip_cooperative_groups.h>
#include <math.h>

namespace cg = cooperative_groups;

// N=512, IN_F=128, OUT_F=64, H=4.
// e_raw[i,j,h] = s1[i][j>>7][h] + s2[j][h]
//   s1[i][g][h] = dot(ht[i][g*64:], a[h][:64]) ; s2[j][h] = dot(ht[j][h*64:], a[h][64:])
// leaky_relu(0.2) -> *ew -> mask adj -> softmax over j
// c[i][h*64+f] = sum_j alpha[i,j,h]*ht[j][h*64+f] ; out = sigmoid(h U^T + c V^T)
//
// Single cooperative kernel, 256 blocks x 512 thr (1 block/CU, co-resident).
// grid.sync() replaces the two inter-kernel boundaries of the 3-kernel version.

__device__ __forceinline__ float wave_sum(float v) {
    #pragma unroll
    for (int o = 32; o; o >>= 1) v += __shfl_xor(v, o, 64);
    return v;
}
__device__ __forceinline__ float wave_max(float v) {
    #pragma unroll
    for (int o = 32; o; o >>= 1) v = fmaxf(v, __shfl_xor(v, o, 64));
    return v;
}

__global__ __launch_bounds__(512) void k_all(
    const float* __restrict__ h, const int* __restrict__ adj,
    const float* __restrict__ ew, const float* __restrict__ W,
    const float* __restrict__ a, const float* __restrict__ U,
    const float* __restrict__ V,
    float* __restrict__ ht, float* __restrict__ s1, float* __restrict__ s2p,
    float* __restrict__ c, float* __restrict__ out)
{
    __shared__ float att[8 * 512];   // 16 KB: scores -> exp -> partial-c
    __shared__ float s2sh[512];
    __shared__ float s1sh[32];
    __shared__ float hsh[2 * 128];
    __shared__ float ash[512];       // a[4][128]
    __shared__ float hts[2 * 256];
    __shared__ float csh[2 * 256];

    const int t = threadIdx.x;
    const int bid = blockIdx.x;

    // ---------------- Phase A: ht rows bid*2 .. bid*2+1, plus s1/s2 ----------------
    {
        const int i0 = bid * 2;
        if (t < 64)       ((float4*)hsh)[t]      = ((const float4*)(h + i0 * 128))[t];
        else if (t < 192) ((float4*)ash)[t - 64] = ((const float4*)a)[t - 64];
        __syncthreads();

        const int r = t >> 8, col = t & 255;
        float acc = 0.f;
        const float4* Wv = (const float4*)(W + col * 128);
        const float* hp = hsh + r * 128;
        #pragma unroll
        for (int kk = 0; kk < 32; ++kk) {
            float4 w4 = Wv[kk];
            acc += w4.x * hp[kk*4] + w4.y * hp[kk*4+1] + w4.z * hp[kk*4+2] + w4.w * hp[kk*4+3];
        }
        ht[(i0 + r) * 256 + col] = acc;
        hts[r * 256 + col] = acc;
        __syncthreads();

        // 40 small dots: t<40, rr=t&1, o=t>>1. o<16 -> s1, o>=16 -> s2.
        if (t < 40) {
            const int rr = t & 1, o = t >> 1;
            const float* x;
            const float* y;
            if (o < 16) { x = hts + rr * 256 + (o >> 2) * 64;  y = ash + (o & 3) * 128; }
            else        { x = hts + rr * 256 + (o - 16) * 64;  y = ash + (o - 16) * 128 + 64; }
            float s = 0.f;
            #pragma unroll
            for (int ff = 0; ff < 64; ++ff) {
                int f = (ff + (t << 3)) & 63;   // bank stagger
                s += x[f] * y[f];
            }
            if (o < 16) s1[(i0 + rr) * 16 + (o >> 2) * 4 + (o & 3)] = s;
            else        s2p[(o - 16) * 512 + i0 + rr] = s;
        }
    }

    cg::this_grid().sync();

    // ---------------- Phase B: attention + aggregate for (i-tile, head) ----------------
    {
        const int hh = bid & 3;
        const int i0 = (bid >> 2) * 8;

        s2sh[t] = s2p[hh * 512 + t];
        if (t < 32) s1sh[t] = s1[(i0 + (t >> 2)) * 16 + (t & 3) * 4 + hh];
        __syncthreads();

        #pragma unroll
        for (int pass = 0; pass < 8; ++pass) {
            int idx = pass * 512 + t;
            int r = idx >> 9, j = idx & 511;
            float e = s1sh[r * 4 + (j >> 7)] + s2sh[j];
            e = (e >= 0.f) ? e : 0.2f * e;
            e *= ew[(i0 + r) * 512 + j];
            att[idx] = (adj[(i0 + r) * 512 + j] > 0) ? e : -9.0e15f;
        }
        __syncthreads();

        const int w = t >> 6, lane = t & 63;
        {   // softmax of row w (exp stored in place)
            float m = -INFINITY;
            #pragma unroll
            for (int k = 0; k < 8; ++k) m = fmaxf(m, att[w * 512 + k * 64 + lane]);
            m = wave_max(m);
            float s = 0.f;
            #pragma unroll
            for (int k = 0; k < 8; ++k) {
                float v = __expf(att[w * 512 + k * 64 + lane] - m);
                s += v;
                att[w * 512 + k * 64 + lane] = v;
            }
            s = wave_sum(s);
            float inv = 1.f / s;
            #pragma unroll
            for (int k = 0; k < 8; ++k) att[w * 512 + k * 64 + lane] *= inv;
        }
        __syncthreads();

        // aggregate: wave w covers j in [w*64, w*64+64) for all 8 rows
        float pacc[8] = {0.f, 0.f, 0.f, 0.f, 0.f, 0.f, 0.f, 0.f};
        const float* htp = ht + hh * 64 + lane;
        const int jbase = w * 64;
        #pragma unroll 4
        for (int jj = 0; jj < 64; jj += 4) {
            const int j = jbase + jj;
            float hv0 = htp[(j + 0) * 256];
            float hv1 = htp[(j + 1) * 256];
            float hv2 = htp[(j + 2) * 256];
            float hv3 = htp[(j + 3) * 256];
            #pragma unroll
            for (int rr = 0; rr < 8; ++rr) {
                float4 ar = *(const float4*)&att[rr * 512 + j];  // LDS broadcast
                pacc[rr] += ar.x * hv0 + ar.y * hv1 + ar.z * hv2 + ar.w * hv3;
            }
        }
        __syncthreads();
        #pragma unroll
        for (int rr = 0; rr < 8; ++rr) att[w * 512 + rr * 64 + lane] = pacc[rr];
        __syncthreads();
        float s = 0.f;
        #pragma unroll
        for (int v8 = 0; v8 < 8; ++v8) s += att[v8 * 512 + w * 64 + lane];
        c[(i0 + w) * 256 + hh * 64 + lane] = s;
    }

    cg::this_grid().sync();

    // ---------------- Phase C: out rows bid*2 .. bid*2+1 ----------------
    {
        const int i0 = bid * 2;
        if (t < 64)       ((float4*)hsh)[t]      = ((const float4*)(h + i0 * 128))[t];
        else if (t < 192) ((float4*)csh)[t - 64] = ((const float4*)(c + i0 * 256))[t - 64];
        __syncthreads();

        const int r = t >> 8, col = t & 255;
        float acc = 0.f;
        const float4* Uv = (const float4*)(U + col * 128);
        const float* hp = hsh + r * 128;
        #pragma unroll
        for (int kk = 0; kk < 32; ++kk) {
            float4 u4 = Uv[kk];
            acc += u4.x * hp[kk*4] + u4.y * hp[kk*4+1] + u4.z * hp[kk*4+2] + u4.w * hp[kk*4+3];
        }
        const float4* Vv = (const float4*)(V + col * 256);
        const float* cp = csh + r * 256;
        #pragma unroll
        for (int kk = 0; kk < 64; ++kk) {
            float4 v4 = Vv[kk];
            acc += v4.x * cp[kk*4] + v4.y * cp[kk*4+1] + v4.z * cp[kk*4+2] + v4.w * cp[kk*4+3];
        }
        out[(i0 + r) * 256 + col] = 1.f / (1.f + __expf(-acc));
    }
}

extern "C" void kernel_launch(void* const* d_in, const int* in_sizes, int n_in,
                              void* d_out, int out_size, void* d_ws, size_t ws_size,
                              hipStream_t stream) {
    const float* h   = (const float*)d_in[0];
    const int*   adj = (const int*)d_in[1];
    const float* ew  = (const float*)d_in[2];
    const float* W   = (const float*)d_in[3];
    const float* a   = (const float*)d_in[4];
    const float* U   = (const float*)d_in[5];
    const float* V   = (const float*)d_in[6];
    float* out = (float*)d_out;

    float* ht  = (float*)d_ws;           // 512*256
    float* s1  = ht + 512 * 256;         // 512*16
    float* s2p = s1 + 512 * 16;          // 4*512
    float* c   = s2p + 4 * 512;          // 512*256

    void* args[] = {
        (void*)&h, (void*)&adj, (void*)&ew, (void*)&W, (void*)&a,
        (void*)&U, (void*)&V, (void*)&ht, (void*)&s1, (void*)&s2p,
        (void*)&c, (void*)&out
    };
    hipLaunchCooperativeKernel((const void*)k_all, dim3(256), dim3(512),
                               args, 0, stream);
}

// Round 5
// 32.117 us; speedup vs baseline: 3.3717x; 3.3717x over previous
//
#include <hip/hip_runtime.h>
#include <math.h>

// N=512, IN_F=128, OUT_F=64, H=4.
// e_raw[i,j,h] = s1[i][j>>7][h] + s2[j][h]
//   s1[i][g][h] = dot(ht[i][g*64:], a[h][:64]) ; s2[j][h] = dot(ht[j][h*64:], a[h][64:])
// leaky_relu(0.2) -> *ew -> mask adj -> softmax over j
// c[i][h*64+f] = sum_j alpha[i,j,h]*ht[j][h*64+f] ; out = sigmoid(h U^T + c V^T)

__device__ __forceinline__ float wave_sum(float v) {
    #pragma unroll
    for (int o = 32; o; o >>= 1) v += __shfl_xor(v, o, 64);
    return v;
}
__device__ __forceinline__ float wave_max(float v) {
    #pragma unroll
    for (int o = 32; o; o >>= 1) v = fmaxf(v, __shfl_xor(v, o, 64));
    return v;
}
__device__ __forceinline__ unsigned bf16rn(float x) {   // round-to-nearest-even bf16
    unsigned u = __float_as_uint(x);
    return (u + 0x7fffu + ((u >> 16) & 1u)) >> 16;
}
__device__ __forceinline__ float asf(unsigned u) { return __uint_as_float(u); }

// ---------------- K1: ht = h @ W^T, plus s1, s2 (round-2 proven) ----------------
// 256 blocks x 256 thr, 2 rows/block.
__global__ __launch_bounds__(256) void k_transform(
    const float* __restrict__ h, const float* __restrict__ W,
    const float* __restrict__ a,
    float* __restrict__ ht, float* __restrict__ s1, float* __restrict__ s2p)
{
    __shared__ float hsh[2 * 128];
    __shared__ float ash[512];      // a[4][128]
    __shared__ float hts[2 * 256];  // this block's ht rows
    const int t = threadIdx.x;
    const int i0 = blockIdx.x * 2;
    if (t < 64)       ((float4*)hsh)[t]      = ((const float4*)(h + i0 * 128))[t];
    else if (t < 192) ((float4*)ash)[t - 64] = ((const float4*)a)[t - 64];
    __syncthreads();

    float acc0 = 0.f, acc1 = 0.f;
    const float4* Wv = (const float4*)(W + t * 128);
    #pragma unroll
    for (int kk = 0; kk < 32; ++kk) {
        float4 w4 = Wv[kk];
        const float* h0 = hsh + kk * 4;
        const float* h1 = hsh + 128 + kk * 4;
        acc0 += w4.x * h0[0] + w4.y * h0[1] + w4.z * h0[2] + w4.w * h0[3];
        acc1 += w4.x * h1[0] + w4.y * h1[1] + w4.z * h1[2] + w4.w * h1[3];
    }
    ht[i0 * 256 + t]       = acc0;
    ht[(i0 + 1) * 256 + t] = acc1;
    hts[t]       = acc0;
    hts[256 + t] = acc1;
    __syncthreads();

    if (t < 40) {
        const int rr = t & 1, o = t >> 1;
        const float* x;
        const float* y;
        if (o < 16) { x = hts + rr * 256 + (o >> 2) * 64;  y = ash + (o & 3) * 128; }
        else        { x = hts + rr * 256 + (o - 16) * 64;  y = ash + (o - 16) * 128 + 64; }
        float s = 0.f;
        #pragma unroll
        for (int ff = 0; ff < 64; ++ff) {
            int f = (ff + (t << 3)) & 63;   // bank stagger
            s += x[f] * y[f];
        }
        if (o < 16) s1[(i0 + rr) * 16 + (o >> 2) * 4 + (o & 3)] = s;
        else        s2p[(o - 16) * 512 + i0 + rr] = s;
    }
}

// ---------------- K2: attention + aggregate ----------------
// 256 blocks (64 i-tiles x 4 heads) x 512 thr (8 waves).
// scores f32 in LDS -> softmax per wave (lane = 8 consecutive j) -> raw exp
// packed bf16x2 -> aggregation reads half the LDS bytes; 1/sum deferred.
__global__ __launch_bounds__(512) void k_att(
    const int* __restrict__ adj, const float* __restrict__ ew,
    const float* __restrict__ ht, const float* __restrict__ s1,
    const float* __restrict__ s2p, float* __restrict__ c)
{
    __shared__ float scores[8 * 512];       // 16 KB, reused for partial-c reduce
    __shared__ unsigned attw[8 * 256];      // 8 KB: exp packed bf16x2 (j even|odd)
    __shared__ float s2sh[512];
    __shared__ float s1sh[32];
    __shared__ float invsh[8];
    const int t = threadIdx.x;
    const int hh = blockIdx.x & 3;
    const int i0 = (blockIdx.x >> 2) * 8;

    s2sh[t] = s2p[hh * 512 + t];
    if (t < 32) s1sh[t] = s1[(i0 + (t >> 2)) * 16 + (t & 3) * 4 + hh];
    __syncthreads();

    // scores: thread = (row r, 8 consecutive j)
    {
        const int r = t >> 6, jj = (t & 63) * 8;
        const float s1v = s1sh[r * 4 + (jj >> 7)];
        #pragma unroll
        for (int q = 0; q < 2; ++q) {
            const int jq = jj + q * 4;
            int4   av = *(const int4*)  (adj + (i0 + r) * 512 + jq);
            float4 wv = *(const float4*)(ew  + (i0 + r) * 512 + jq);
            float4 sv = *(const float4*)&s2sh[jq];
            float4 o;
            float e;
            e = s1v + sv.x; e = (e >= 0.f) ? e : 0.2f * e; e *= wv.x; o.x = (av.x > 0) ? e : -9.0e15f;
            e = s1v + sv.y; e = (e >= 0.f) ? e : 0.2f * e; e *= wv.y; o.y = (av.y > 0) ? e : -9.0e15f;
            e = s1v + sv.z; e = (e >= 0.f) ? e : 0.2f * e; e *= wv.z; o.z = (av.z > 0) ? e : -9.0e15f;
            e = s1v + sv.w; e = (e >= 0.f) ? e : 0.2f * e; e *= wv.w; o.w = (av.w > 0) ? e : -9.0e15f;
            *(float4*)&scores[r * 512 + jq] = o;
        }
    }
    __syncthreads();

    // softmax row w: lane owns 8 consecutive j -> pack exp as bf16x2, b128 store
    const int w = t >> 6, lane = t & 63;
    {
        float v[8];
        float4 v0 = *(const float4*)&scores[w * 512 + lane * 8];
        float4 v1 = *(const float4*)&scores[w * 512 + lane * 8 + 4];
        v[0]=v0.x; v[1]=v0.y; v[2]=v0.z; v[3]=v0.w;
        v[4]=v1.x; v[5]=v1.y; v[6]=v1.z; v[7]=v1.w;
        float m = v[0];
        #pragma unroll
        for (int k = 1; k < 8; ++k) m = fmaxf(m, v[k]);
        m = wave_max(m);
        float s = 0.f;
        #pragma unroll
        for (int k = 0; k < 8; ++k) { v[k] = __expf(v[k] - m); s += v[k]; }
        s = wave_sum(s);
        if (lane == 0) invsh[w] = 1.f / s;
        uint4 pk;
        pk.x = bf16rn(v[0]) | (bf16rn(v[1]) << 16);
        pk.y = bf16rn(v[2]) | (bf16rn(v[3]) << 16);
        pk.z = bf16rn(v[4]) | (bf16rn(v[5]) << 16);
        pk.w = bf16rn(v[6]) | (bf16rn(v[7]) << 16);
        *(uint4*)&attw[w * 256 + lane * 4] = pk;
    }
    __syncthreads();

    // aggregate: wave w covers j in [w*64, w*64+64) for all 8 rows
    float pacc[8] = {0.f, 0.f, 0.f, 0.f, 0.f, 0.f, 0.f, 0.f};
    const float* htp = ht + hh * 64 + lane;
    const int jbase = w * 64;
    for (int g = 0; g < 8; ++g) {
        const int j = jbase + g * 8;
        float hv[8];
        #pragma unroll
        for (int q = 0; q < 8; ++q) hv[q] = htp[(j + q) * 256];
        #pragma unroll
        for (int r = 0; r < 8; ++r) {
            uint4 av = *(const uint4*)&attw[r * 256 + (j >> 1)];   // broadcast
            pacc[r] += asf(av.x << 16) * hv[0] + asf(av.x & 0xffff0000u) * hv[1]
                     + asf(av.y << 16) * hv[2] + asf(av.y & 0xffff0000u) * hv[3]
                     + asf(av.z << 16) * hv[4] + asf(av.z & 0xffff0000u) * hv[5]
                     + asf(av.w << 16) * hv[6] + asf(av.w & 0xffff0000u) * hv[7];
        }
    }
    __syncthreads();
    #pragma unroll
    for (int r = 0; r < 8; ++r) scores[r * 512 + w * 64 + lane] = pacc[r];
    __syncthreads();
    {
        const int r = t >> 6, f = t & 63;
        float s = 0.f;
        #pragma unroll
        for (int v8 = 0; v8 < 8; ++v8) s += scores[r * 512 + v8 * 64 + f];
        c[(i0 + r) * 256 + hh * 64 + f] = s * invsh[r];
    }
}

// ---------------- K3: out = sigmoid(h U^T + c V^T) ----------------
// 128 blocks x 512 thr, 4 rows/block, K-split: half 0 = U[0:64]+V[0:128],
// half 1 = U[64:128]+V[128:256]. Every weight element read once per block.
__global__ __launch_bounds__(512) void k_out(
    const float* __restrict__ h, const float* __restrict__ cbuf,
    const float* __restrict__ U, const float* __restrict__ V,
    float* __restrict__ out)
{
    __shared__ float hsh[4 * 128];
    __shared__ float csh[4 * 256];
    __shared__ float psum[2 * 4 * 256];   // [half][row][col]
    const int t = threadIdx.x;
    const int i0 = blockIdx.x * 4;
    if (t < 128)      ((float4*)hsh)[t]       = ((const float4*)(h + i0 * 128))[t];
    else if (t < 384) ((float4*)csh)[t - 128] = ((const float4*)(cbuf + i0 * 256))[t - 128];
    __syncthreads();

    const int col = t & 255, half = t >> 8;
    float acc[4] = {0.f, 0.f, 0.f, 0.f};
    {
        const float4* Uv = (const float4*)(U + col * 128 + half * 64);
        #pragma unroll
        for (int kk = 0; kk < 16; ++kk) {
            float4 u4 = Uv[kk];
            const int k0 = half * 64 + kk * 4;
            #pragma unroll
            for (int r = 0; r < 4; ++r) {
                const float* hp = hsh + r * 128 + k0;
                acc[r] += u4.x * hp[0] + u4.y * hp[1] + u4.z * hp[2] + u4.w * hp[3];
            }
        }
        const float4* Vv = (const float4*)(V + col * 256 + half * 128);
        #pragma unroll
        for (int kk = 0; kk < 32; ++kk) {
            float4 v4 = Vv[kk];
            const int k0 = half * 128 + kk * 4;
            #pragma unroll
            for (int r = 0; r < 4; ++r) {
                const float* cp = csh + r * 256 + k0;
                acc[r] += v4.x * cp[0] + v4.y * cp[1] + v4.z * cp[2] + v4.w * cp[3];
            }
        }
    }
    #pragma unroll
    for (int r = 0; r < 4; ++r) psum[(half * 4 + r) * 256 + col] = acc[r];
    __syncthreads();
    {
        const int rr = t >> 8;   // handles rows rr*2, rr*2+1
        #pragma unroll
        for (int q = 0; q < 2; ++q) {
            const int r = rr * 2 + q;
            float x = psum[r * 256 + col] + psum[(4 + r) * 256 + col];
            out[(i0 + r) * 256 + col] = 1.f / (1.f + __expf(-x));
        }
    }
}

extern "C" void kernel_launch(void* const* d_in, const int* in_sizes, int n_in,
                              void* d_out, int out_size, void* d_ws, size_t ws_size,
                              hipStream_t stream) {
    const float* h   = (const float*)d_in[0];
    const int*   adj = (const int*)d_in[1];
    const float* ew  = (const float*)d_in[2];
    const float* W   = (const float*)d_in[3];
    const float* a   = (const float*)d_in[4];
    const float* U   = (const float*)d_in[5];
    const float* V   = (const float*)d_in[6];
    float* out = (float*)d_out;

    float* ht  = (float*)d_ws;           // 512*256
    float* s1  = ht + 512 * 256;         // 512*16
    float* s2p = s1 + 512 * 16;          // 4*512
    float* c   = s2p + 4 * 512;          // 512*256

    k_transform<<<256, 256, 0, stream>>>(h, W, a, ht, s1, s2p);
    k_att<<<256, 512, 0, stream>>>(adj, ew, ht, s1, s2p, c);
    k_out<<<128, 512, 0, stream>>>(h, c, U, V, out);
}

// Round 6
// 30.950 us; speedup vs baseline: 3.4987x; 1.0377x over previous
//
#include <hip/hip_runtime.h>
#include <math.h>

// N=512, IN_F=128, OUT_F=64, H=4.
// e_raw[i,j,h] = s1[i][j>>7][h] + s2[j][h]
//   s1[i][g][h] = dot(ht[i][g*64:], a[h][:64]) ; s2[j][h] = dot(ht[j][h*64:], a[h][64:])
// leaky_relu(0.2) -> *ew -> mask adj -> softmax over j
// c[i][h*64+f] = sum_j alpha[i,j,h]*ht[j][h*64+f] ; out = sigmoid(h U^T + c V^T)

__device__ __forceinline__ float wave_sum(float v) {
    #pragma unroll
    for (int o = 32; o; o >>= 1) v += __shfl_xor(v, o, 64);
    return v;
}
__device__ __forceinline__ float wave_max(float v) {
    #pragma unroll
    for (int o = 32; o; o >>= 1) v = fmaxf(v, __shfl_xor(v, o, 64));
    return v;
}
__device__ __forceinline__ unsigned bf16rn(float x) {   // round-to-nearest-even bf16
    unsigned u = __float_as_uint(x);
    return (u + 0x7fffu + ((u >> 16) & 1u)) >> 16;
}
__device__ __forceinline__ float asf(unsigned u) { return __uint_as_float(u); }

// ---------------- K1: ht = h @ W^T, plus s1, s2 (round-2 proven) ----------------
// 256 blocks x 256 thr, 2 rows/block.
__global__ __launch_bounds__(256) void k_transform(
    const float* __restrict__ h, const float* __restrict__ W,
    const float* __restrict__ a,
    float* __restrict__ ht, float* __restrict__ s1, float* __restrict__ s2p)
{
    __shared__ float hsh[2 * 128];
    __shared__ float ash[512];      // a[4][128]
    __shared__ float hts[2 * 256];  // this block's ht rows
    const int t = threadIdx.x;
    const int i0 = blockIdx.x * 2;
    if (t < 64)       ((float4*)hsh)[t]      = ((const float4*)(h + i0 * 128))[t];
    else if (t < 192) ((float4*)ash)[t - 64] = ((const float4*)a)[t - 64];
    __syncthreads();

    float acc0 = 0.f, acc1 = 0.f;
    const float4* Wv = (const float4*)(W + t * 128);
    #pragma unroll
    for (int kk = 0; kk < 32; ++kk) {
        float4 w4 = Wv[kk];
        const float* h0 = hsh + kk * 4;
        const float* h1 = hsh + 128 + kk * 4;
        acc0 += w4.x * h0[0] + w4.y * h0[1] + w4.z * h0[2] + w4.w * h0[3];
        acc1 += w4.x * h1[0] + w4.y * h1[1] + w4.z * h1[2] + w4.w * h1[3];
    }
    ht[i0 * 256 + t]       = acc0;
    ht[(i0 + 1) * 256 + t] = acc1;
    hts[t]       = acc0;
    hts[256 + t] = acc1;
    __syncthreads();

    if (t < 40) {
        const int rr = t & 1, o = t >> 1;
        const float* x;
        const float* y;
        if (o < 16) { x = hts + rr * 256 + (o >> 2) * 64;  y = ash + (o & 3) * 128; }
        else        { x = hts + rr * 256 + (o - 16) * 64;  y = ash + (o - 16) * 128 + 64; }
        float s = 0.f;
        #pragma unroll
        for (int ff = 0; ff < 64; ++ff) {
            int f = (ff + (t << 3)) & 63;   // bank stagger
            s += x[f] * y[f];
        }
        if (o < 16) s1[(i0 + rr) * 16 + (o >> 2) * 4 + (o & 3)] = s;
        else        s2p[(o - 16) * 512 + i0 + rr] = s;
    }
}

// ---------------- K2: attention + aggregate ----------------
// 512 blocks (128 i-tiles x 4 heads) x 512 thr (8 waves) -> 2 blocks/CU.
// 4 rows/block. Softmax: wave w handles (row w>>1, j-half w&1); max/sum
// combined across wave pairs via LDS. Alpha exp packed bf16x2; 1/sum deferred.
__global__ __launch_bounds__(512) void k_att(
    const int* __restrict__ adj, const float* __restrict__ ew,
    const float* __restrict__ ht, const float* __restrict__ s1,
    const float* __restrict__ s2p, float* __restrict__ c)
{
    __shared__ float scores[4 * 512];       // 8 KB, reused for partial-c reduce
    __shared__ unsigned attw[4 * 256];      // 4 KB: exp packed bf16x2
    __shared__ float s2sh[512];
    __shared__ float s1sh[16];
    __shared__ float mloc[8], sloc[8];
    const int t = threadIdx.x;
    const int hh = blockIdx.x & 3;
    const int i0 = (blockIdx.x >> 2) * 4;

    s2sh[t] = s2p[hh * 512 + t];
    if (t < 16) s1sh[t] = s1[(i0 + (t >> 2)) * 16 + (t & 3) * 4 + hh];
    __syncthreads();

    // scores: thread = (row r = t>>7, 4 consecutive j)
    {
        const int r = t >> 7, j4 = (t & 127) * 4;
        const float s1v = s1sh[r * 4 + (j4 >> 7)];
        int4   av = *(const int4*)  (adj + (i0 + r) * 512 + j4);
        float4 wv = *(const float4*)(ew  + (i0 + r) * 512 + j4);
        float4 sv = *(const float4*)&s2sh[j4];
        float4 o; float e;
        e = s1v + sv.x; e = (e >= 0.f) ? e : 0.2f * e; e *= wv.x; o.x = (av.x > 0) ? e : -9.0e15f;
        e = s1v + sv.y; e = (e >= 0.f) ? e : 0.2f * e; e *= wv.y; o.y = (av.y > 0) ? e : -9.0e15f;
        e = s1v + sv.z; e = (e >= 0.f) ? e : 0.2f * e; e *= wv.z; o.z = (av.z > 0) ? e : -9.0e15f;
        e = s1v + sv.w; e = (e >= 0.f) ? e : 0.2f * e; e *= wv.w; o.w = (av.w > 0) ? e : -9.0e15f;
        *(float4*)&scores[r * 512 + j4] = o;
    }
    __syncthreads();

    // softmax: wave w = (row r = w>>1, j-half jh = w&1); lane owns 4 consecutive j
    const int w = t >> 6, lane = t & 63;
    {
        const int r = w >> 1, jh = w & 1;
        float4 v4 = *(const float4*)&scores[r * 512 + jh * 256 + lane * 4];
        float m = fmaxf(fmaxf(v4.x, v4.y), fmaxf(v4.z, v4.w));
        m = wave_max(m);
        if (lane == 0) mloc[w] = m;
        __syncthreads();
        m = fmaxf(mloc[r * 2], mloc[r * 2 + 1]);
        float e0 = __expf(v4.x - m), e1 = __expf(v4.y - m);
        float e2 = __expf(v4.z - m), e3 = __expf(v4.w - m);
        float s = wave_sum((e0 + e1) + (e2 + e3));
        if (lane == 0) sloc[w] = s;
        uint2 pk;
        pk.x = bf16rn(e0) | (bf16rn(e1) << 16);
        pk.y = bf16rn(e2) | (bf16rn(e3) << 16);
        *(uint2*)&attw[r * 256 + jh * 128 + lane * 2] = pk;   // u32[k] = j{2k,2k+1}
    }
    __syncthreads();

    // aggregate: wave w covers j in [w*64, w*64+64) for all 4 rows
    float pacc[4] = {0.f, 0.f, 0.f, 0.f};
    const float* htp = ht + hh * 64 + lane;
    const int jbase = w * 64;
    for (int g = 0; g < 8; ++g) {
        const int j = jbase + g * 8;
        float hv[8];
        #pragma unroll
        for (int q = 0; q < 8; ++q) hv[q] = htp[(j + q) * 256];
        #pragma unroll
        for (int r = 0; r < 4; ++r) {
            uint4 av = *(const uint4*)&attw[r * 256 + (j >> 1)];   // broadcast
            pacc[r] += asf(av.x << 16) * hv[0] + asf(av.x & 0xffff0000u) * hv[1]
                     + asf(av.y << 16) * hv[2] + asf(av.y & 0xffff0000u) * hv[3]
                     + asf(av.z << 16) * hv[4] + asf(av.z & 0xffff0000u) * hv[5]
                     + asf(av.w << 16) * hv[6] + asf(av.w & 0xffff0000u) * hv[7];
        }
    }
    __syncthreads();
    #pragma unroll
    for (int r = 0; r < 4; ++r) scores[w * 256 + r * 64 + lane] = pacc[r];
    __syncthreads();
    if (t < 256) {
        const int r = t >> 6, f = t & 63;
        float s = 0.f;
        #pragma unroll
        for (int w8 = 0; w8 < 8; ++w8) s += scores[w8 * 256 + r * 64 + f];
        float inv = 1.f / (sloc[r * 2] + sloc[r * 2 + 1]);
        c[(i0 + r) * 256 + hh * 64 + f] = s * inv;
    }
}

// ---------------- K3: out = sigmoid(h U^T + c V^T) (round-5 proven) ----------------
// 128 blocks x 512 thr, 4 rows/block, K-split across thread halves.
__global__ __launch_bounds__(512) void k_out(
    const float* __restrict__ h, const float* __restrict__ cbuf,
    const float* __restrict__ U, const float* __restrict__ V,
    float* __restrict__ out)
{
    __shared__ float hsh[4 * 128];
    __shared__ float csh[4 * 256];
    __shared__ float psum[2 * 4 * 256];   // [half][row][col]
    const int t = threadIdx.x;
    const int i0 = blockIdx.x * 4;
    if (t < 128)      ((float4*)hsh)[t]       = ((const float4*)(h + i0 * 128))[t];
    else if (t < 384) ((float4*)csh)[t - 128] = ((const float4*)(cbuf + i0 * 256))[t - 128];
    __syncthreads();

    const int col = t & 255, half = t >> 8;
    float acc[4] = {0.f, 0.f, 0.f, 0.f};
    {
        const float4* Uv = (const float4*)(U + col * 128 + half * 64);
        #pragma unroll
        for (int kk = 0; kk < 16; ++kk) {
            float4 u4 = Uv[kk];
            const int k0 = half * 64 + kk * 4;
            #pragma unroll
            for (int r = 0; r < 4; ++r) {
                const float* hp = hsh + r * 128 + k0;
                acc[r] += u4.x * hp[0] + u4.y * hp[1] + u4.z * hp[2] + u4.w * hp[3];
            }
        }
        const float4* Vv = (const float4*)(V + col * 256 + half * 128);
        #pragma unroll
        for (int kk = 0; kk < 32; ++kk) {
            float4 v4 = Vv[kk];
            const int k0 = half * 128 + kk * 4;
            #pragma unroll
            for (int r = 0; r < 4; ++r) {
                const float* cp = csh + r * 256 + k0;
                acc[r] += v4.x * cp[0] + v4.y * cp[1] + v4.z * cp[2] + v4.w * cp[3];
            }
        }
    }
    #pragma unroll
    for (int r = 0; r < 4; ++r) psum[(half * 4 + r) * 256 + col] = acc[r];
    __syncthreads();
    {
        const int rr = t >> 8;   // handles rows rr*2, rr*2+1
        #pragma unroll
        for (int q = 0; q < 2; ++q) {
            const int r = rr * 2 + q;
            float x = psum[r * 256 + col] + psum[(4 + r) * 256 + col];
            out[(i0 + r) * 256 + col] = 1.f / (1.f + __expf(-x));
        }
    }
}

extern "C" void kernel_launch(void* const* d_in, const int* in_sizes, int n_in,
                              void* d_out, int out_size, void* d_ws, size_t ws_size,
                              hipStream_t stream) {
    const float* h   = (const float*)d_in[0];
    const int*   adj = (const int*)d_in[1];
    const float* ew  = (const float*)d_in[2];
    const float* W   = (const float*)d_in[3];
    const float* a   = (const float*)d_in[4];
    const float* U   = (const float*)d_in[5];
    const float* V   = (const float*)d_in[6];
    float* out = (float*)d_out;

    float* ht  = (float*)d_ws;           // 512*256
    float* s1  = ht + 512 * 256;         // 512*16
    float* s2p = s1 + 512 * 16;          // 4*512
    float* c   = s2p + 4 * 512;          // 512*256

    k_transform<<<256, 256, 0, stream>>>(h, W, a, ht, s1, s2p);
    k_att<<<512, 512, 0, stream>>>(adj, ew, ht, s1, s2p, c);
    k_out<<<128, 512, 0, stream>>>(h, c, U, V, out);
}